// Round 11
// baseline (144.284 us; speedup 1.0000x reference)
//
#include <hip/hip_runtime.h>
#include <hip/hip_bf16.h>

// Problem dims (fixed by reference)
#define BB 4
#define ENC_LEN 1024
#define DEC_LEN 256
#define ENC_H 1024
#define ATTN_A 256

#define C2F 2.8853900817779268f  // 2*log2(e)

typedef short bf16x8 __attribute__((ext_vector_type(8)));
typedef float f32x4 __attribute__((ext_vector_type(4)));
typedef unsigned int u32x2 __attribute__((ext_vector_type(2)));

union Q2D {
  uint4 q;
  u32x2 d[2];
};
union BF8 {
  u32x2 d[2];
  bf16x8 v;
};

// fp32 -> bf16 round-to-nearest-even
static __device__ __forceinline__ unsigned short f2bf(float x) {
  union {
    float f;
    unsigned int u;
  } c;
  c.f = x;
  unsigned int r = c.u + 0x7FFFu + ((c.u >> 16) & 1u);
  return (unsigned short)(r >> 16);
}

// ---------------------------------------------------------------------------
// prep: all conversions/transposes in one dispatch (1408 blocks).
//  [0,64):      Wh [1024h][256a] -> WhT bf16 [256a][1024h]
//  [64,128):    Ws -> WsT
//  [128,1152):  enc[b][e][h] -> encT bf16 [b][h][e]  AND  encB bf16 [b][e][h]
//  [1152,1408): dec -> decB bf16 (row-major convert only)
// ---------------------------------------------------------------------------
__global__ __launch_bounds__(256) void prep_k(
    const float* __restrict__ Wh, const float* __restrict__ Ws,
    const float* __restrict__ enc, const float* __restrict__ dec,
    unsigned short* __restrict__ WhT, unsigned short* __restrict__ WsT,
    unsigned short* __restrict__ encT, unsigned short* __restrict__ encB,
    unsigned short* __restrict__ decB) {
  __shared__ unsigned short T[64][68];
  const int wb = blockIdx.x;
  const int t = threadIdx.x;
  const int lr = t >> 4;
  const int lc4 = (t & 15) * 4;

  if (wb >= 1152) {
    const int q = wb - 1152;
    const int r0 = (q >> 4) * 64;
    const int c0 = (q & 15) * 64;
#pragma unroll
    for (int p = 0; p < 4; ++p) {
      const int r = lr + p * 16;
      const float4 v = *(const float4*)&dec[(long)(r0 + r) * ENC_H + c0 + lc4];
      ushort4 o;
      o.x = f2bf(v.x);
      o.y = f2bf(v.y);
      o.z = f2bf(v.z);
      o.w = f2bf(v.w);
      *(ushort4*)&decB[(long)(r0 + r) * ENC_H + c0 + lc4] = o;
    }
    return;
  }

  const float* in;
  unsigned short* out;
  unsigned short* out2 = nullptr;  // row-major bf16 copy (enc only)
  int R, C, bx, by;
  if (wb < 128) {
    in = (wb < 64) ? Wh : Ws;
    out = (wb < 64) ? WhT : WsT;
    const int tt = wb & 63;
    R = ENC_H;
    C = ATTN_A;
    bx = tt & 3;
    by = tt >> 2;
  } else {
    const int tt0 = wb - 128;
    const int b = tt0 >> 8;
    const int tt = tt0 & 255;
    in = enc + (long)b * ENC_LEN * ENC_H;
    out = encT + (long)b * ENC_H * ENC_LEN;
    out2 = encB + (long)b * ENC_LEN * ENC_H;
    R = ENC_LEN;
    C = ENC_H;
    bx = tt & 15;
    by = tt >> 4;
  }
  const int r0 = by * 64;
  const int c0 = bx * 64;

#pragma unroll
  for (int p = 0; p < 4; ++p) {
    const int r = lr + p * 16;
    const float4 v = *(const float4*)&in[(long)(r0 + r) * C + c0 + lc4];
    ushort4 o;
    o.x = f2bf(v.x);
    o.y = f2bf(v.y);
    o.z = f2bf(v.z);
    o.w = f2bf(v.w);
    *(ushort4*)&T[r][lc4] = o;
    if (out2) *(ushort4*)&out2[(long)(r0 + r) * C + c0 + lc4] = o;
  }
  __syncthreads();
#pragma unroll
  for (int p = 0; p < 4; ++p) {
    const int c = lr + p * 16;
    ushort4 o;
    o.x = T[lc4 + 0][c];
    o.y = T[lc4 + 1][c];
    o.z = T[lc4 + 2][c];
    o.w = T[lc4 + 3][c];
    *(ushort4*)&out[(long)(c0 + c) * R + r0 + lc4] = o;
  }
}

// ---------------------------------------------------------------------------
// Projection GEMM, tile 32x64, FULL K=1024 (no K-split -> no partials).
// grid (4, 160): y < 32: pd (M=1024, m0=y*32); y >= 32: pe (M=4096).
// 4 waves: wave covers 16 rows x 32 cols = 2 mfma_16x16x32. Register prefetch.
// pd out: pdP[m][a] = C2*proj.  pe out (E-TILED): peP[b][et][a][eo] = C2*proj.
// ---------------------------------------------------------------------------
__global__ __launch_bounds__(256) void pgemm(const unsigned short* __restrict__ decB,
                                             const unsigned short* __restrict__ encB,
                                             const unsigned short* __restrict__ WsT,
                                             const unsigned short* __restrict__ WhT,
                                             float* __restrict__ pdP,
                                             float* __restrict__ peP) {
  __shared__ unsigned short As[32][36];
  __shared__ unsigned short Bs[64][36];
  __shared__ float Cs[64][36];

  const bool isPD = blockIdx.y < 32;
  const unsigned short* A = isPD ? decB : encB;
  const unsigned short* BT = isPD ? WsT : WhT;
  const int m0 = (isPD ? blockIdx.y : (blockIdx.y - 32)) * 32;
  const int n0 = blockIdx.x * 64;

  const int tid = threadIdx.x;
  const int lane = tid & 63;
  const int wave = tid >> 6;
  const int quad = lane >> 4;
  const int l16 = lane & 15;
  const int wm = (wave >> 1) * 16;
  const int wn = (wave & 1) * 32;
  const int sr = tid >> 2;          // 0..63 (B rows)
  const int ar = (tid >> 2) & 31;   // 0..31 (A rows; valid loads for tid<128)
  const int sk = (tid & 3) * 8;

  f32x4 acc[2] = {{0.f, 0.f, 0.f, 0.f}, {0.f, 0.f, 0.f, 0.f}};

  const unsigned short* Ap = A + (long)(m0 + ar) * ENC_H + sk;
  const unsigned short* Bp = BT + (long)(n0 + sr) * ENC_H + sk;

  Q2D av, bv;
  if (tid < 128) av.q = *(const uint4*)(Ap);
  bv.q = *(const uint4*)(Bp);

  for (int k0 = 0; k0 < 1024; k0 += 32) {
    __syncthreads();
    if (tid < 128) {
      *(u32x2*)&As[ar][sk] = av.d[0];
      *(u32x2*)&As[ar][sk + 4] = av.d[1];
    }
    *(u32x2*)&Bs[sr][sk] = bv.d[0];
    *(u32x2*)&Bs[sr][sk + 4] = bv.d[1];
    const int kn = (k0 + 32 < 1024) ? (k0 + 32) : 0;
    if (tid < 128) av.q = *(const uint4*)(Ap + kn);
    bv.q = *(const uint4*)(Bp + kn);
    __syncthreads();

    bf16x8 af, bfr[2];
    {
      BF8 t;
      t.d[0] = *(const u32x2*)&As[wm + l16][quad * 8];
      t.d[1] = *(const u32x2*)&As[wm + l16][quad * 8 + 4];
      af = t.v;
    }
#pragma unroll
    for (int j = 0; j < 2; ++j) {
      BF8 t;
      t.d[0] = *(const u32x2*)&Bs[wn + j * 16 + l16][quad * 8];
      t.d[1] = *(const u32x2*)&Bs[wn + j * 16 + l16][quad * 8 + 4];
      bfr[j] = t.v;
    }
#pragma unroll
    for (int j = 0; j < 2; ++j)
      acc[j] = __builtin_amdgcn_mfma_f32_16x16x32_bf16(af, bfr[j], acc[j], 0, 0, 0);
  }

  if (isPD) {
#pragma unroll
    for (int j = 0; j < 2; ++j) {
      const int col = n0 + wn + j * 16 + l16;
      const int row = m0 + wm + quad * 4;
#pragma unroll
      for (int r = 0; r < 4; ++r)
        pdP[(long)(row + r) * ATTN_A + col] = C2F * acc[j][r];
    }
  } else {
    // Cs[a][e] then E-TILED write: peP[b][et][a][eo]
#pragma unroll
    for (int j = 0; j < 2; ++j)
#pragma unroll
      for (int r = 0; r < 4; ++r)
        Cs[wn + j * 16 + l16][wm + quad * 4 + r] = C2F * acc[j][r];
    __syncthreads();
    const int gb = m0 >> 10;
    const int e0 = m0 & 1023;
    const int et = e0 >> 8;
    const int eoff = e0 & 255;
    float* out = peP + (long)gb * (ATTN_A * ENC_LEN) + (long)et * (ATTN_A * 256);
#pragma unroll
    for (int p = 0; p < 2; ++p) {
      const int slot = tid + p * 256;
      const int arow = slot >> 3;
      const int e4 = (slot & 7) * 4;
      const float4 o = *(const float4*)&Cs[arow][e4];
      *(float4*)&out[(long)(n0 + arow) * 256 + eoff + e4] = o;
    }
  }
}

// ---------------------------------------------------------------------------
// Logits, single peP (no split), a-split x4, E-TILED contiguous reads.
// Grid (4, 32, 16): z = b*4 + aq. Block: 64 a's, 8 d's, 256 e's.
// EdT[dd][a] = exp2(pd + C2*bs); Ee = exp2(pe); batched rcp; 2-deep prefetch.
// ---------------------------------------------------------------------------
__global__ __launch_bounds__(256) void logits_k(const float* __restrict__ peP,
                                                const float* __restrict__ pdP,
                                                const float* __restrict__ v,
                                                const float* __restrict__ bs,
                                                float* __restrict__ p0,
                                                float* __restrict__ p1,
                                                float* __restrict__ p2,
                                                float* __restrict__ p3) {
  const int tid = threadIdx.x;
  const int et = blockIdx.x;
  const int e = et * 256 + tid;
  const int d0 = blockIdx.y * 8;
  const int b = blockIdx.z >> 2;
  const int aq = blockIdx.z & 3;
  const int a0 = aq * 64;

  __shared__ float EdT[8][64];  // [dd][a]
  __shared__ float vv[64];

  {
    const int a = tid & 63;
    const int dh = tid >> 6;
    const float cb = C2F * bs[a0 + a];
#pragma unroll
    for (int j = 0; j < 2; ++j) {
      const int dd = dh * 2 + j;
      const long idx = (long)(b * DEC_LEN + d0 + dd) * ATTN_A + a0 + a;
      EdT[dd][a] = __builtin_amdgcn_exp2f(pdP[idx] + cb);
    }
    if (dh == 0) vv[a] = -2.0f * v[a0 + a];
  }
  __syncthreads();

  float acc[8] = {0.f, 0.f, 0.f, 0.f, 0.f, 0.f, 0.f, 0.f};
  const float* pe = peP + (long)b * (ATTN_A * ENC_LEN) + (long)et * (ATTN_A * 256) +
                    (long)a0 * 256 + tid;

  float pA[4], pB[4];
#pragma unroll
  for (int u = 0; u < 4; ++u) {
    pA[u] = pe[u * 256];
    pB[u] = pe[(4 + u) * 256];
  }

  for (int a4 = 0; a4 < 64; a4 += 4) {
    float Ee[4];
#pragma unroll
    for (int u = 0; u < 4; ++u) Ee[u] = __builtin_amdgcn_exp2f(pA[u]);
    const int an = (a4 + 8 < 64) ? (a4 + 8) : 0;
#pragma unroll
    for (int u = 0; u < 4; ++u) {
      pA[u] = pB[u];
      pB[u] = pe[(an + u) * 256];
    }
    const float4 v4 = *(const float4*)&vv[a4];

#pragma unroll
    for (int dd = 0; dd < 8; ++dd) {
      const float4 ed = *(const float4*)&EdT[dd][a4];  // broadcast read
      const float dn0 = fmaf(ed.x, Ee[0], 1.0f);
      const float dn1 = fmaf(ed.y, Ee[1], 1.0f);
      const float dn2 = fmaf(ed.z, Ee[2], 1.0f);
      const float dn3 = fmaf(ed.w, Ee[3], 1.0f);
      const float x12 = dn0 * dn1;
      const float x34 = dn2 * dn3;
      float t1 = v4.x * dn1;
      t1 = fmaf(v4.y, dn0, t1);
      float t2 = v4.z * dn3;
      t2 = fmaf(v4.w, dn2, t2);
      float num = t1 * x34;
      num = fmaf(t2, x12, num);
      const float D = x12 * x34;
      const float r = __builtin_amdgcn_rcpf(D);
      acc[dd] = fmaf(num, r, acc[dd]);
    }
  }

  float* po = (aq == 0) ? p0 : (aq == 1) ? p1 : (aq == 2) ? p2 : p3;
  const long base = ((long)(b * DEC_LEN + d0) * ENC_LEN) + e;
#pragma unroll
  for (int dd = 0; dd < 8; ++dd) po[base + (long)dd * ENC_LEN] = acc[dd];
}

// ---------------------------------------------------------------------------
// Masked softmax over e: logits = p0+p1+p2+p3; fp32 result to p0 (attn) and
// bf16 copy to attnB (for cgemm).
// ---------------------------------------------------------------------------
__global__ __launch_bounds__(256) void softmax4_k(float* __restrict__ p0,
                                                  const float* __restrict__ p1,
                                                  const float* __restrict__ p2,
                                                  const float* __restrict__ p3,
                                                  const float* __restrict__ mask,
                                                  unsigned short* __restrict__ attnB) {
  const int row = blockIdx.x;
  const int b = row >> 8;
  const int tid = threadIdx.x;
  float* rp = p0 + (long)row * ENC_LEN;
  const float* rq1 = p1 + (long)row * ENC_LEN;
  const float* rq2 = p2 + (long)row * ENC_LEN;
  const float* rq3 = p3 + (long)row * ENC_LEN;
  const float* mp = mask + b * ENC_LEN;
  unsigned short* rb = attnB + (long)row * ENC_LEN;

  float l[4], m[4];
#pragma unroll
  for (int j = 0; j < 4; ++j) {
    const int i = tid + 256 * j;
    l[j] = (rp[i] + rq1[i]) + (rq2[i] + rq3[i]);
    m[j] = mp[i];
  }

  __shared__ float redmax[4];
  __shared__ float redsum[4];
  const int lane = tid & 63;
  const int wid = tid >> 6;

  float tm = fmaxf(fmaxf(l[0], l[1]), fmaxf(l[2], l[3]));
#pragma unroll
  for (int off = 1; off < 64; off <<= 1) tm = fmaxf(tm, __shfl_xor(tm, off, 64));
  if (lane == 0) redmax[wid] = tm;
  __syncthreads();
  const float rmax = fmaxf(fmaxf(redmax[0], redmax[1]), fmaxf(redmax[2], redmax[3]));

  const float LOG2E = 1.4426950408889634f;
  float p[4];
  float ts = 0.f;
#pragma unroll
  for (int j = 0; j < 4; ++j) {
    p[j] = __builtin_amdgcn_exp2f((l[j] - rmax) * LOG2E) * m[j];
    ts += p[j];
  }
#pragma unroll
  for (int off = 1; off < 64; off <<= 1) ts += __shfl_xor(ts, off, 64);
  if (lane == 0) redsum[wid] = ts;
  __syncthreads();
  const float rsum = redsum[0] + redsum[1] + redsum[2] + redsum[3];

  const float inv = 1.0f / rsum;
#pragma unroll
  for (int j = 0; j < 4; ++j) {
    const float w = p[j] * inv;
    rp[tid + 256 * j] = w;
    rb[tid + 256 * j] = f2bf(w);
  }
}

// ---------------------------------------------------------------------------
// ctx GEMM, tile 32x64, FULL K=1024, writes ctx directly (no creduce).
// grid (16, 8, 4): n0 = x*64 (h), m0 = y*32 (d), b = z. 512 blocks.
// ---------------------------------------------------------------------------
__global__ __launch_bounds__(256) void cgemm(const unsigned short* __restrict__ attnB,
                                             const unsigned short* __restrict__ encT,
                                             float* __restrict__ ctx) {
  __shared__ unsigned short As[32][36];
  __shared__ unsigned short Bs[64][36];

  const int b = blockIdx.z;
  const unsigned short* A = attnB + (long)b * DEC_LEN * ENC_LEN;
  const unsigned short* BT = encT + (long)b * ENC_H * ENC_LEN;
  float* C = ctx + (long)b * DEC_LEN * ENC_H;

  const int tid = threadIdx.x;
  const int lane = tid & 63;
  const int wave = tid >> 6;
  const int quad = lane >> 4;
  const int l16 = lane & 15;
  const int wm = (wave >> 1) * 16;
  const int wn = (wave & 1) * 32;
  const int m0 = blockIdx.y * 32;
  const int n0 = blockIdx.x * 64;
  const int sr = tid >> 2;
  const int ar = (tid >> 2) & 31;
  const int sk = (tid & 3) * 8;

  f32x4 acc[2] = {{0.f, 0.f, 0.f, 0.f}, {0.f, 0.f, 0.f, 0.f}};

  const unsigned short* Ap = A + (long)(m0 + ar) * ENC_LEN + sk;
  const unsigned short* Bp = BT + (long)(n0 + sr) * ENC_LEN + sk;

  Q2D av, bv;
  if (tid < 128) av.q = *(const uint4*)(Ap);
  bv.q = *(const uint4*)(Bp);

  for (int k0 = 0; k0 < 1024; k0 += 32) {
    __syncthreads();
    if (tid < 128) {
      *(u32x2*)&As[ar][sk] = av.d[0];
      *(u32x2*)&As[ar][sk + 4] = av.d[1];
    }
    *(u32x2*)&Bs[sr][sk] = bv.d[0];
    *(u32x2*)&Bs[sr][sk + 4] = bv.d[1];
    const int kn = (k0 + 32 < 1024) ? (k0 + 32) : 0;
    if (tid < 128) av.q = *(const uint4*)(Ap + kn);
    bv.q = *(const uint4*)(Bp + kn);
    __syncthreads();

    bf16x8 af, bfr[2];
    {
      BF8 t;
      t.d[0] = *(const u32x2*)&As[wm + l16][quad * 8];
      t.d[1] = *(const u32x2*)&As[wm + l16][quad * 8 + 4];
      af = t.v;
    }
#pragma unroll
    for (int j = 0; j < 2; ++j) {
      BF8 t;
      t.d[0] = *(const u32x2*)&Bs[wn + j * 16 + l16][quad * 8];
      t.d[1] = *(const u32x2*)&Bs[wn + j * 16 + l16][quad * 8 + 4];
      bfr[j] = t.v;
    }
#pragma unroll
    for (int j = 0; j < 2; ++j)
      acc[j] = __builtin_amdgcn_mfma_f32_16x16x32_bf16(af, bfr[j], acc[j], 0, 0, 0);
  }

#pragma unroll
  for (int j = 0; j < 2; ++j) {
    const int col = n0 + wn + j * 16 + l16;
    const int row = m0 + wm + quad * 4;
#pragma unroll
    for (int r = 0; r < 4; ++r) C[(long)(row + r) * ENC_H + col] = acc[j][r];
  }
}

// ---------------------------------------------------------------------------
// Fallback fp32 path kernels (proven, used only if ws too small)
// ---------------------------------------------------------------------------
template <int OMODE, bool BIAS>
__global__ __launch_bounds__(256) void gemm64(const float* __restrict__ A,
                                              const float* __restrict__ B,
                                              const float* __restrict__ bias,
                                              float* __restrict__ C,
                                              int K, int lda, int ldb, int ldc,
                                              long sA, long sB, long sC) {
  const int bz = blockIdx.z;
  A += (long)bz * sA;
  B += (long)bz * sB;
  C += (long)bz * sC;

  const int tid = threadIdx.x;
  const int tx = tid & 15;
  const int ty = tid >> 4;

  __shared__ float As2[16][64];
  __shared__ float Bs2[16][64];

  float acc[4][4];
#pragma unroll
  for (int i = 0; i < 4; ++i)
#pragma unroll
    for (int j = 0; j < 4; ++j) acc[i][j] = 0.f;

  const int ar = tid >> 2;
  const int ak4 = (tid & 3) << 2;
  const int br = tid >> 4;
  const int bn4 = (tid & 15) << 2;

  const float* Aload = A + (long)(blockIdx.y * 64 + ar) * lda + ak4;
  const float* Bload = B + (long)br * ldb + blockIdx.x * 64 + bn4;

  for (int k0 = 0; k0 < K; k0 += 16) {
    const float4 av = *(const float4*)(Aload + k0);
    const float4 bv = *(const float4*)(Bload + (long)k0 * ldb);
    __syncthreads();
    As2[ak4 + 0][ar] = av.x;
    As2[ak4 + 1][ar] = av.y;
    As2[ak4 + 2][ar] = av.z;
    As2[ak4 + 3][ar] = av.w;
    *(float4*)&Bs2[br][bn4] = bv;
    __syncthreads();
#pragma unroll
    for (int kk = 0; kk < 16; ++kk) {
      const float4 a4 = *(const float4*)&As2[kk][ty << 2];
      const float4 b4 = *(const float4*)&Bs2[kk][tx << 2];
      const float am[4] = {a4.x, a4.y, a4.z, a4.w};
      const float bn[4] = {b4.x, b4.y, b4.z, b4.w};
#pragma unroll
      for (int i = 0; i < 4; ++i)
#pragma unroll
        for (int j = 0; j < 4; ++j) acc[i][j] = fmaf(am[i], bn[j], acc[i][j]);
    }
  }

  if (OMODE == 0) {
    const int row0 = blockIdx.y * 64 + (ty << 2);
    const int col0 = blockIdx.x * 64 + (tx << 2);
    float4 bb4 = make_float4(0.f, 0.f, 0.f, 0.f);
    if (BIAS) bb4 = *(const float4*)&bias[col0];
#pragma unroll
    for (int i = 0; i < 4; ++i) {
      float4 o;
      o.x = acc[i][0] + bb4.x;
      o.y = acc[i][1] + bb4.y;
      o.z = acc[i][2] + bb4.z;
      o.w = acc[i][3] + bb4.w;
      *(float4*)&C[(long)(row0 + i) * ldc + col0] = o;
    }
  } else {
#pragma unroll
    for (int i = 0; i < 4; ++i) {
      const int gr = blockIdx.y * 64 + (ty << 2) + i;
      const int b = gr >> 10;
      const int e = gr & 1023;
#pragma unroll
      for (int j = 0; j < 4; ++j) {
        const int col = blockIdx.x * 64 + (tx << 2) + j;
        C[(long)b * (ATTN_A * ENC_LEN) + (long)col * ENC_LEN + e] = acc[i][j];
      }
    }
  }
}

__global__ __launch_bounds__(256) void logits_fb(const float* __restrict__ peT,
                                                 const float* __restrict__ pd,
                                                 const float* __restrict__ v,
                                                 float* __restrict__ out) {
  const int tid = threadIdx.x;
  const int e = blockIdx.x * 256 + tid;
  const int d0 = blockIdx.y * 8;
  const int b = blockIdx.z;

  __shared__ float cpd[ATTN_A][8];
  __shared__ float vv[ATTN_A];

  {
    const int a = tid;
#pragma unroll
    for (int dd = 0; dd < 8; ++dd)
      cpd[a][dd] = C2F * pd[((b * DEC_LEN + d0 + dd) * ATTN_A) + a];
    vv[a] = -2.0f * v[a];
  }
  __syncthreads();

  float acc[8] = {0.f, 0.f, 0.f, 0.f, 0.f, 0.f, 0.f, 0.f};
  const float* pe = peT + (long)b * (ATTN_A * ENC_LEN) + e;

  for (int a = 0; a < ATTN_A; a += 4) {
    float pes[4];
#pragma unroll
    for (int u = 0; u < 4; ++u) pes[u] = pe[(long)(a + u) * ENC_LEN];
#pragma unroll
    for (int u = 0; u < 4; ++u) {
      const float cpe = C2F * pes[u];
      const float vu = vv[a + u];
      const float4 c0 = *(const float4*)&cpd[a + u][0];
      const float4 c1 = *(const float4*)&cpd[a + u][4];
      const float cd[8] = {c0.x, c0.y, c0.z, c0.w, c1.x, c1.y, c1.z, c1.w};
#pragma unroll
      for (int dd = 0; dd < 8; ++dd) {
        const float x = cd[dd] + cpe;
        const float ex = __builtin_amdgcn_exp2f(x);
        const float r = __builtin_amdgcn_rcpf(ex + 1.0f);
        acc[dd] = fmaf(vu, r, acc[dd]);
      }
    }
  }

  const long base = ((long)(b * DEC_LEN + d0) * ENC_LEN) + e;
#pragma unroll
  for (int dd = 0; dd < 8; ++dd) out[base + (long)dd * ENC_LEN] = acc[dd];
}

__global__ __launch_bounds__(256) void softmax_fb(float* __restrict__ attn,
                                                  const float* __restrict__ mask) {
  const int row = blockIdx.x;
  const int b = row >> 8;
  const int tid = threadIdx.x;
  float* rp = attn + (long)row * ENC_LEN;
  const float* mp = mask + b * ENC_LEN;

  float l[4], m[4];
#pragma unroll
  for (int j = 0; j < 4; ++j) {
    l[j] = rp[tid + 256 * j];
    m[j] = mp[tid + 256 * j];
  }

  __shared__ float redmax[4];
  __shared__ float redsum[4];
  const int lane = tid & 63;
  const int wid = tid >> 6;

  float tm = fmaxf(fmaxf(l[0], l[1]), fmaxf(l[2], l[3]));
#pragma unroll
  for (int off = 1; off < 64; off <<= 1) tm = fmaxf(tm, __shfl_xor(tm, off, 64));
  if (lane == 0) redmax[wid] = tm;
  __syncthreads();
  const float rmax = fmaxf(fmaxf(redmax[0], redmax[1]), fmaxf(redmax[2], redmax[3]));

  const float LOG2E = 1.4426950408889634f;
  float p[4];
  float ts = 0.f;
#pragma unroll
  for (int j = 0; j < 4; ++j) {
    p[j] = __builtin_amdgcn_exp2f((l[j] - rmax) * LOG2E) * m[j];
    ts += p[j];
  }
#pragma unroll
  for (int off = 1; off < 64; off <<= 1) ts += __shfl_xor(ts, off, 64);
  if (lane == 0) redsum[wid] = ts;
  __syncthreads();
  const float rsum = redsum[0] + redsum[1] + redsum[2] + redsum[3];

  const float inv = 1.0f / rsum;
#pragma unroll
  for (int j = 0; j < 4; ++j) rp[tid + 256 * j] = p[j] * inv;
}

// ---------------------------------------------------------------------------
extern "C" void kernel_launch(void* const* d_in, const int* in_sizes, int n_in,
                              void* d_out, int out_size, void* d_ws, size_t ws_size,
                              hipStream_t stream) {
  const float* enc = (const float*)d_in[0];
  const float* dec = (const float*)d_in[1];
  const float* mask = (const float*)d_in[2];
  const float* Wh = (const float*)d_in[3];
  const float* Ws = (const float*)d_in[4];
  const float* bs = (const float*)d_in[5];
  const float* v = (const float*)d_in[6];

  float* ctx = (float*)d_out;                      // [4,256,1024]
  float* attn = ctx + (long)BB * DEC_LEN * ENC_H;  // [4,256,1024]

  // ws layout (fast path):
  //  pdP  f32 [1024][256]             1 MB
  //  peP  f32 [4][4et][256a][256eo]   4 MB   (E-TILED, single — no K-split)
  //  p1,p2,p3 f32 [4][256][1024] each 12 MB (logits partials, aq=1..3)
  //  encT bf16 [4][1024h][1024e]      8 MB
  //  WhT/WsT bf16 [256][1024]         1 MB
  //  encB bf16 [4][1024e][1024h]      8 MB
  //  decB bf16 [1024][1024]           2 MB
  //  attnB bf16 [4][256][1024]        2 MB
  const long N_PD = 1024L * ATTN_A;
  const long N_PE = (long)BB * ATTN_A * ENC_LEN;
  const long N_P1 = (long)BB * DEC_LEN * ENC_LEN;
  const long N_ENC = (long)BB * ENC_H * ENC_LEN;
  const long N_W = (long)ATTN_A * ENC_H;
  const long N_DEC = 1024L * ENC_H;
  const long N_ATT = (long)BB * DEC_LEN * ENC_LEN;
  const size_t FAST_WS = (N_PD + N_PE + 3 * N_P1) * 4 +
                         (N_ENC + 2 * N_W + N_ENC + N_DEC + N_ATT) * 2;

  if (ws_size >= FAST_WS) {
    float* pdP = (float*)d_ws;
    float* peP = pdP + N_PD;
    float* p1 = peP + N_PE;
    float* p2 = p1 + N_P1;
    float* p3 = p2 + N_P1;
    unsigned short* encT = (unsigned short*)(p3 + N_P1);
    unsigned short* WhT = encT + N_ENC;
    unsigned short* WsT = WhT + N_W;
    unsigned short* encB = WsT + N_W;
    unsigned short* decB = encB + N_ENC;
    unsigned short* attnB = decB + N_DEC;

    // 1) all transposes + bf16 conversions
    prep_k<<<dim3(1408, 1, 1), 256, 0, stream>>>(Wh, Ws, enc, dec, WhT, WsT, encT,
                                                 encB, decB);
    // 2) projections, tile 32x64, full K (640 blocks, no partials)
    pgemm<<<dim3(4, 160, 1), 256, 0, stream>>>(decB, encB, WsT, WhT, pdP, peP);
    // 3) logits partials: a-split x4, single-peP contiguous reads
    logits_k<<<dim3(4, 32, BB * 4), 256, 0, stream>>>(peP, pdP, v, bs, attn, p1, p2,
                                                      p3);
    // 4) masked softmax (sum of 4 partials) -> attn (fp32) + attnB (bf16)
    softmax4_k<<<dim3(BB * DEC_LEN, 1, 1), 256, 0, stream>>>(attn, p1, p2, p3, mask,
                                                             attnB);
    // 5) ctx GEMM, tile 32x64, full K, direct write (512 blocks, no creduce)
    cgemm<<<dim3(16, 8, BB), 256, 0, stream>>>(attnB, encT, ctx);
  } else {
    // fallback: proven fp32 path (5 MB ws)
    float* pd = (float*)d_ws;
    float* peT = pd + (long)BB * DEC_LEN * ATTN_A;

    gemm64<0, true><<<dim3(ATTN_A / 64, (BB * DEC_LEN) / 64, 1), 256, 0, stream>>>(
        dec, Ws, bs, pd, ENC_H, ENC_H, ATTN_A, ATTN_A, 0, 0, 0);
    gemm64<1, false><<<dim3(ATTN_A / 64, (BB * ENC_LEN) / 64, 1), 256, 0, stream>>>(
        enc, Wh, nullptr, peT, ENC_H, ENC_H, ATTN_A, 0, 0, 0, 0);
    logits_fb<<<dim3(ENC_LEN / 256, DEC_LEN / 8, BB), 256, 0, stream>>>(peT, pd, v,
                                                                        attn);
    softmax_fb<<<dim3(BB * DEC_LEN, 1, 1), 256, 0, stream>>>(attn, mask);
    gemm64<0, false><<<dim3(ENC_H / 64, DEC_LEN / 64, BB), 256, 0, stream>>>(
        attn, enc, nullptr, ctx, ENC_LEN, ENC_LEN, ENC_H, ENC_H,
        (long)DEC_LEN * ENC_LEN, (long)ENC_LEN * ENC_H, (long)DEC_LEN * ENC_H);
  }
}

// Round 12
// 143.388 us; speedup vs baseline: 1.0062x; 1.0062x over previous
//
#include <hip/hip_runtime.h>
#include <hip/hip_bf16.h>

// Problem dims (fixed by reference)
#define BB 4
#define ENC_LEN 1024
#define DEC_LEN 256
#define ENC_H 1024
#define ATTN_A 256

#define C2F 2.8853900817779268f  // 2*log2(e)

typedef short bf16x8 __attribute__((ext_vector_type(8)));
typedef float f32x4 __attribute__((ext_vector_type(4)));
typedef unsigned int u32x2 __attribute__((ext_vector_type(2)));

union Q2D {
  uint4 q;
  u32x2 d[2];
};
union BF8 {
  u32x2 d[2];
  bf16x8 v;
};

// fp32 -> bf16 round-to-nearest-even
static __device__ __forceinline__ unsigned short f2bf(float x) {
  union {
    float f;
    unsigned int u;
  } c;
  c.f = x;
  unsigned int r = c.u + 0x7FFFu + ((c.u >> 16) & 1u);
  return (unsigned short)(r >> 16);
}

// ---------------------------------------------------------------------------
// prep: all conversions/transposes in one dispatch (1408 blocks).
//  [0,64):      Wh [1024h][256a] -> WhT bf16 [256a][1024h]
//  [64,128):    Ws -> WsT
//  [128,1152):  enc[b][e][h] -> encT bf16 [b][h][e]  AND  encB bf16 [b][e][h]
//  [1152,1408): dec -> decB bf16 (row-major convert only)
// ---------------------------------------------------------------------------
__global__ __launch_bounds__(256) void prep_k(
    const float* __restrict__ Wh, const float* __restrict__ Ws,
    const float* __restrict__ enc, const float* __restrict__ dec,
    unsigned short* __restrict__ WhT, unsigned short* __restrict__ WsT,
    unsigned short* __restrict__ encT, unsigned short* __restrict__ encB,
    unsigned short* __restrict__ decB) {
  __shared__ unsigned short T[64][68];
  const int wb = blockIdx.x;
  const int t = threadIdx.x;
  const int lr = t >> 4;
  const int lc4 = (t & 15) * 4;

  if (wb >= 1152) {
    const int q = wb - 1152;
    const int r0 = (q >> 4) * 64;
    const int c0 = (q & 15) * 64;
#pragma unroll
    for (int p = 0; p < 4; ++p) {
      const int r = lr + p * 16;
      const float4 v = *(const float4*)&dec[(long)(r0 + r) * ENC_H + c0 + lc4];
      ushort4 o;
      o.x = f2bf(v.x);
      o.y = f2bf(v.y);
      o.z = f2bf(v.z);
      o.w = f2bf(v.w);
      *(ushort4*)&decB[(long)(r0 + r) * ENC_H + c0 + lc4] = o;
    }
    return;
  }

  const float* in;
  unsigned short* out;
  unsigned short* out2 = nullptr;  // row-major bf16 copy (enc only)
  int R, C, bx, by;
  if (wb < 128) {
    in = (wb < 64) ? Wh : Ws;
    out = (wb < 64) ? WhT : WsT;
    const int tt = wb & 63;
    R = ENC_H;
    C = ATTN_A;
    bx = tt & 3;
    by = tt >> 2;
  } else {
    const int tt0 = wb - 128;
    const int b = tt0 >> 8;
    const int tt = tt0 & 255;
    in = enc + (long)b * ENC_LEN * ENC_H;
    out = encT + (long)b * ENC_H * ENC_LEN;
    out2 = encB + (long)b * ENC_LEN * ENC_H;
    R = ENC_LEN;
    C = ENC_H;
    bx = tt & 15;
    by = tt >> 4;
  }
  const int r0 = by * 64;
  const int c0 = bx * 64;

#pragma unroll
  for (int p = 0; p < 4; ++p) {
    const int r = lr + p * 16;
    const float4 v = *(const float4*)&in[(long)(r0 + r) * C + c0 + lc4];
    ushort4 o;
    o.x = f2bf(v.x);
    o.y = f2bf(v.y);
    o.z = f2bf(v.z);
    o.w = f2bf(v.w);
    *(ushort4*)&T[r][lc4] = o;
    if (out2) *(ushort4*)&out2[(long)(r0 + r) * C + c0 + lc4] = o;
  }
  __syncthreads();
#pragma unroll
  for (int p = 0; p < 4; ++p) {
    const int c = lr + p * 16;
    ushort4 o;
    o.x = T[lc4 + 0][c];
    o.y = T[lc4 + 1][c];
    o.z = T[lc4 + 2][c];
    o.w = T[lc4 + 3][c];
    *(ushort4*)&out[(long)(c0 + c) * R + r0 + lc4] = o;
  }
}

// ---------------------------------------------------------------------------
// Projection GEMM, tile 32x64, FULL K=1024 (no K-split -> no partials).
// grid (4, 160): y < 32: pd (M=1024, m0=y*32); y >= 32: pe (M=4096).
// pd out: pdE[m][a] = exp2(C2*(proj + bs[a]))  (exp fused into epilogue).
// pe out (E-TILED): peP[b][et][a][eo] = C2*proj.
// ---------------------------------------------------------------------------
__global__ __launch_bounds__(256) void pgemm(const unsigned short* __restrict__ decB,
                                             const unsigned short* __restrict__ encB,
                                             const unsigned short* __restrict__ WsT,
                                             const unsigned short* __restrict__ WhT,
                                             const float* __restrict__ bs,
                                             float* __restrict__ pdE,
                                             float* __restrict__ peP) {
  __shared__ unsigned short As[32][36];
  __shared__ unsigned short Bs[64][36];
  __shared__ float Cs[64][36];

  const bool isPD = blockIdx.y < 32;
  const unsigned short* A = isPD ? decB : encB;
  const unsigned short* BT = isPD ? WsT : WhT;
  const int m0 = (isPD ? blockIdx.y : (blockIdx.y - 32)) * 32;
  const int n0 = blockIdx.x * 64;

  const int tid = threadIdx.x;
  const int lane = tid & 63;
  const int wave = tid >> 6;
  const int quad = lane >> 4;
  const int l16 = lane & 15;
  const int wm = (wave >> 1) * 16;
  const int wn = (wave & 1) * 32;
  const int sr = tid >> 2;
  const int ar = (tid >> 2) & 31;
  const int sk = (tid & 3) * 8;

  f32x4 acc[2] = {{0.f, 0.f, 0.f, 0.f}, {0.f, 0.f, 0.f, 0.f}};

  const unsigned short* Ap = A + (long)(m0 + ar) * ENC_H + sk;
  const unsigned short* Bp = BT + (long)(n0 + sr) * ENC_H + sk;

  Q2D av, bv;
  if (tid < 128) av.q = *(const uint4*)(Ap);
  bv.q = *(const uint4*)(Bp);

  for (int k0 = 0; k0 < 1024; k0 += 32) {
    __syncthreads();
    if (tid < 128) {
      *(u32x2*)&As[ar][sk] = av.d[0];
      *(u32x2*)&As[ar][sk + 4] = av.d[1];
    }
    *(u32x2*)&Bs[sr][sk] = bv.d[0];
    *(u32x2*)&Bs[sr][sk + 4] = bv.d[1];
    const int kn = (k0 + 32 < 1024) ? (k0 + 32) : 0;
    if (tid < 128) av.q = *(const uint4*)(Ap + kn);
    bv.q = *(const uint4*)(Bp + kn);
    __syncthreads();

    bf16x8 af, bfr[2];
    {
      BF8 t;
      t.d[0] = *(const u32x2*)&As[wm + l16][quad * 8];
      t.d[1] = *(const u32x2*)&As[wm + l16][quad * 8 + 4];
      af = t.v;
    }
#pragma unroll
    for (int j = 0; j < 2; ++j) {
      BF8 t;
      t.d[0] = *(const u32x2*)&Bs[wn + j * 16 + l16][quad * 8];
      t.d[1] = *(const u32x2*)&Bs[wn + j * 16 + l16][quad * 8 + 4];
      bfr[j] = t.v;
    }
#pragma unroll
    for (int j = 0; j < 2; ++j)
      acc[j] = __builtin_amdgcn_mfma_f32_16x16x32_bf16(af, bfr[j], acc[j], 0, 0, 0);
  }

  if (isPD) {
#pragma unroll
    for (int j = 0; j < 2; ++j) {
      const int col = n0 + wn + j * 16 + l16;
      const int row = m0 + wm + quad * 4;
      const float bj = bs[col];
#pragma unroll
      for (int r = 0; r < 4; ++r)
        pdE[(long)(row + r) * ATTN_A + col] =
            __builtin_amdgcn_exp2f(C2F * (acc[j][r] + bj));
    }
  } else {
#pragma unroll
    for (int j = 0; j < 2; ++j)
#pragma unroll
      for (int r = 0; r < 4; ++r)
        Cs[wn + j * 16 + l16][wm + quad * 4 + r] = C2F * acc[j][r];
    __syncthreads();
    const int gb = m0 >> 10;
    const int e0 = m0 & 1023;
    const int et = e0 >> 8;
    const int eoff = e0 & 255;
    float* out = peP + (long)gb * (ATTN_A * ENC_LEN) + (long)et * (ATTN_A * 256);
#pragma unroll
    for (int p = 0; p < 2; ++p) {
      const int slot = tid + p * 256;
      const int arow = slot >> 3;
      const int e4 = (slot & 7) * 4;
      const float4 o = *(const float4*)&Cs[arow][e4];
      *(float4*)&out[(long)(n0 + arow) * 256 + eoff + e4] = o;
    }
  }
}

// ---------------------------------------------------------------------------
// Logits: dd=16 per block (halves peP re-read vs dd=8 — viable now that the
// e-tiled layout fixed the R8/R9 L1-set thrash), a-split x4.
// Grid (4, 16, 16): z = b*4 + aq. Block: 64 a's, 16 d's, 256 e's.
// EdT[dd][a] loaded directly from pdE (exp pre-applied in pgemm);
// Ee = exp2(pe); batched rcp (4 a's share one rcp); 2-deep prefetch.
// ---------------------------------------------------------------------------
__global__ __launch_bounds__(256) void logits_k(const float* __restrict__ peP,
                                                const float* __restrict__ pdE,
                                                const float* __restrict__ v,
                                                float* __restrict__ p0,
                                                float* __restrict__ p1,
                                                float* __restrict__ p2,
                                                float* __restrict__ p3) {
  const int tid = threadIdx.x;
  const int et = blockIdx.x;
  const int e = et * 256 + tid;
  const int d0 = blockIdx.y * 16;
  const int b = blockIdx.z >> 2;
  const int aq = blockIdx.z & 3;
  const int a0 = aq * 64;

  __shared__ float EdT[16][64];  // [dd][a]
  __shared__ float vv[64];

  {
    const int a = tid & 63;
    const int dh = tid >> 6;  // 0..3: stages dd = dh*4 .. dh*4+3
#pragma unroll
    for (int j = 0; j < 4; ++j) {
      const int dd = dh * 4 + j;
      EdT[dd][a] = pdE[(long)(b * DEC_LEN + d0 + dd) * ATTN_A + a0 + a];
    }
    if (dh == 0) vv[a] = -2.0f * v[a0 + a];
  }
  __syncthreads();

  float acc[16];
#pragma unroll
  for (int i = 0; i < 16; ++i) acc[i] = 0.f;

  const float* pe = peP + (long)b * (ATTN_A * ENC_LEN) + (long)et * (ATTN_A * 256) +
                    (long)a0 * 256 + tid;

  float pA[4], pB[4];
#pragma unroll
  for (int u = 0; u < 4; ++u) {
    pA[u] = pe[u * 256];
    pB[u] = pe[(4 + u) * 256];
  }

  for (int a4 = 0; a4 < 64; a4 += 4) {
    float Ee[4];
#pragma unroll
    for (int u = 0; u < 4; ++u) Ee[u] = __builtin_amdgcn_exp2f(pA[u]);
    const int an = (a4 + 8 < 64) ? (a4 + 8) : 0;
#pragma unroll
    for (int u = 0; u < 4; ++u) {
      pA[u] = pB[u];
      pB[u] = pe[(an + u) * 256];
    }
    const float4 v4 = *(const float4*)&vv[a4];

#pragma unroll
    for (int dd = 0; dd < 16; ++dd) {
      const float4 ed = *(const float4*)&EdT[dd][a4];  // broadcast read
      const float dn0 = fmaf(ed.x, Ee[0], 1.0f);
      const float dn1 = fmaf(ed.y, Ee[1], 1.0f);
      const float dn2 = fmaf(ed.z, Ee[2], 1.0f);
      const float dn3 = fmaf(ed.w, Ee[3], 1.0f);
      const float x12 = dn0 * dn1;
      const float x34 = dn2 * dn3;
      float t1 = v4.x * dn1;
      t1 = fmaf(v4.y, dn0, t1);
      float t2 = v4.z * dn3;
      t2 = fmaf(v4.w, dn2, t2);
      float num = t1 * x34;
      num = fmaf(t2, x12, num);
      const float D = x12 * x34;
      const float r = __builtin_amdgcn_rcpf(D);
      acc[dd] = fmaf(num, r, acc[dd]);
    }
  }

  float* po = (aq == 0) ? p0 : (aq == 1) ? p1 : (aq == 2) ? p2 : p3;
  const long base = ((long)(b * DEC_LEN + d0) * ENC_LEN) + e;
#pragma unroll
  for (int dd = 0; dd < 16; ++dd) po[base + (long)dd * ENC_LEN] = acc[dd];
}

// ---------------------------------------------------------------------------
// Masked softmax over e: logits = p0+p1+p2+p3; fp32 result to p0 (attn) and
// bf16 copy to attnB (for cgemm).
// ---------------------------------------------------------------------------
__global__ __launch_bounds__(256) void softmax4_k(float* __restrict__ p0,
                                                  const float* __restrict__ p1,
                                                  const float* __restrict__ p2,
                                                  const float* __restrict__ p3,
                                                  const float* __restrict__ mask,
                                                  unsigned short* __restrict__ attnB) {
  const int row = blockIdx.x;
  const int b = row >> 8;
  const int tid = threadIdx.x;
  float* rp = p0 + (long)row * ENC_LEN;
  const float* rq1 = p1 + (long)row * ENC_LEN;
  const float* rq2 = p2 + (long)row * ENC_LEN;
  const float* rq3 = p3 + (long)row * ENC_LEN;
  const float* mp = mask + b * ENC_LEN;
  unsigned short* rb = attnB + (long)row * ENC_LEN;

  float l[4], m[4];
#pragma unroll
  for (int j = 0; j < 4; ++j) {
    const int i = tid + 256 * j;
    l[j] = (rp[i] + rq1[i]) + (rq2[i] + rq3[i]);
    m[j] = mp[i];
  }

  __shared__ float redmax[4];
  __shared__ float redsum[4];
  const int lane = tid & 63;
  const int wid = tid >> 6;

  float tm = fmaxf(fmaxf(l[0], l[1]), fmaxf(l[2], l[3]));
#pragma unroll
  for (int off = 1; off < 64; off <<= 1) tm = fmaxf(tm, __shfl_xor(tm, off, 64));
  if (lane == 0) redmax[wid] = tm;
  __syncthreads();
  const float rmax = fmaxf(fmaxf(redmax[0], redmax[1]), fmaxf(redmax[2], redmax[3]));

  const float LOG2E = 1.4426950408889634f;
  float p[4];
  float ts = 0.f;
#pragma unroll
  for (int j = 0; j < 4; ++j) {
    p[j] = __builtin_amdgcn_exp2f((l[j] - rmax) * LOG2E) * m[j];
    ts += p[j];
  }
#pragma unroll
  for (int off = 1; off < 64; off <<= 1) ts += __shfl_xor(ts, off, 64);
  if (lane == 0) redsum[wid] = ts;
  __syncthreads();
  const float rsum = redsum[0] + redsum[1] + redsum[2] + redsum[3];

  const float inv = 1.0f / rsum;
#pragma unroll
  for (int j = 0; j < 4; ++j) {
    const float w = p[j] * inv;
    rp[tid + 256 * j] = w;
    rb[tid + 256 * j] = f2bf(w);
  }
}

// ---------------------------------------------------------------------------
// ctx GEMM, tile 32x64, FULL K=1024, writes ctx directly.
// grid (16, 8, 4): n0 = x*64 (h), m0 = y*32 (d), b = z. 512 blocks.
// ---------------------------------------------------------------------------
__global__ __launch_bounds__(256) void cgemm(const unsigned short* __restrict__ attnB,
                                             const unsigned short* __restrict__ encT,
                                             float* __restrict__ ctx) {
  __shared__ unsigned short As[32][36];
  __shared__ unsigned short Bs[64][36];

  const int b = blockIdx.z;
  const unsigned short* A = attnB + (long)b * DEC_LEN * ENC_LEN;
  const unsigned short* BT = encT + (long)b * ENC_H * ENC_LEN;
  float* C = ctx + (long)b * DEC_LEN * ENC_H;

  const int tid = threadIdx.x;
  const int lane = tid & 63;
  const int wave = tid >> 6;
  const int quad = lane >> 4;
  const int l16 = lane & 15;
  const int wm = (wave >> 1) * 16;
  const int wn = (wave & 1) * 32;
  const int m0 = blockIdx.y * 32;
  const int n0 = blockIdx.x * 64;
  const int sr = tid >> 2;
  const int ar = (tid >> 2) & 31;
  const int sk = (tid & 3) * 8;

  f32x4 acc[2] = {{0.f, 0.f, 0.f, 0.f}, {0.f, 0.f, 0.f, 0.f}};

  const unsigned short* Ap = A + (long)(m0 + ar) * ENC_LEN + sk;
  const unsigned short* Bp = BT + (long)(n0 + sr) * ENC_LEN + sk;

  Q2D av, bv;
  if (tid < 128) av.q = *(const uint4*)(Ap);
  bv.q = *(const uint4*)(Bp);

  for (int k0 = 0; k0 < 1024; k0 += 32) {
    __syncthreads();
    if (tid < 128) {
      *(u32x2*)&As[ar][sk] = av.d[0];
      *(u32x2*)&As[ar][sk + 4] = av.d[1];
    }
    *(u32x2*)&Bs[sr][sk] = bv.d[0];
    *(u32x2*)&Bs[sr][sk + 4] = bv.d[1];
    const int kn = (k0 + 32 < 1024) ? (k0 + 32) : 0;
    if (tid < 128) av.q = *(const uint4*)(Ap + kn);
    bv.q = *(const uint4*)(Bp + kn);
    __syncthreads();

    bf16x8 af, bfr[2];
    {
      BF8 t;
      t.d[0] = *(const u32x2*)&As[wm + l16][quad * 8];
      t.d[1] = *(const u32x2*)&As[wm + l16][quad * 8 + 4];
      af = t.v;
    }
#pragma unroll
    for (int j = 0; j < 2; ++j) {
      BF8 t;
      t.d[0] = *(const u32x2*)&Bs[wn + j * 16 + l16][quad * 8];
      t.d[1] = *(const u32x2*)&Bs[wn + j * 16 + l16][quad * 8 + 4];
      bfr[j] = t.v;
    }
#pragma unroll
    for (int j = 0; j < 2; ++j)
      acc[j] = __builtin_amdgcn_mfma_f32_16x16x32_bf16(af, bfr[j], acc[j], 0, 0, 0);
  }

#pragma unroll
  for (int j = 0; j < 2; ++j) {
    const int col = n0 + wn + j * 16 + l16;
    const int row = m0 + wm + quad * 4;
#pragma unroll
    for (int r = 0; r < 4; ++r) C[(long)(row + r) * ENC_H + col] = acc[j][r];
  }
}

// ---------------------------------------------------------------------------
// Fallback fp32 path kernels (proven, used only if ws too small)
// ---------------------------------------------------------------------------
template <int OMODE, bool BIAS>
__global__ __launch_bounds__(256) void gemm64(const float* __restrict__ A,
                                              const float* __restrict__ B,
                                              const float* __restrict__ bias,
                                              float* __restrict__ C,
                                              int K, int lda, int ldb, int ldc,
                                              long sA, long sB, long sC) {
  const int bz = blockIdx.z;
  A += (long)bz * sA;
  B += (long)bz * sB;
  C += (long)bz * sC;

  const int tid = threadIdx.x;
  const int tx = tid & 15;
  const int ty = tid >> 4;

  __shared__ float As2[16][64];
  __shared__ float Bs2[16][64];

  float acc[4][4];
#pragma unroll
  for (int i = 0; i < 4; ++i)
#pragma unroll
    for (int j = 0; j < 4; ++j) acc[i][j] = 0.f;

  const int ar = tid >> 2;
  const int ak4 = (tid & 3) << 2;
  const int br = tid >> 4;
  const int bn4 = (tid & 15) << 2;

  const float* Aload = A + (long)(blockIdx.y * 64 + ar) * lda + ak4;
  const float* Bload = B + (long)br * ldb + blockIdx.x * 64 + bn4;

  for (int k0 = 0; k0 < K; k0 += 16) {
    const float4 av = *(const float4*)(Aload + k0);
    const float4 bv = *(const float4*)(Bload + (long)k0 * ldb);
    __syncthreads();
    As2[ak4 + 0][ar] = av.x;
    As2[ak4 + 1][ar] = av.y;
    As2[ak4 + 2][ar] = av.z;
    As2[ak4 + 3][ar] = av.w;
    *(float4*)&Bs2[br][bn4] = bv;
    __syncthreads();
#pragma unroll
    for (int kk = 0; kk < 16; ++kk) {
      const float4 a4 = *(const float4*)&As2[kk][ty << 2];
      const float4 b4 = *(const float4*)&Bs2[kk][tx << 2];
      const float am[4] = {a4.x, a4.y, a4.z, a4.w};
      const float bn[4] = {b4.x, b4.y, b4.z, b4.w};
#pragma unroll
      for (int i = 0; i < 4; ++i)
#pragma unroll
        for (int j = 0; j < 4; ++j) acc[i][j] = fmaf(am[i], bn[j], acc[i][j]);
    }
  }

  if (OMODE == 0) {
    const int row0 = blockIdx.y * 64 + (ty << 2);
    const int col0 = blockIdx.x * 64 + (tx << 2);
    float4 bb4 = make_float4(0.f, 0.f, 0.f, 0.f);
    if (BIAS) bb4 = *(const float4*)&bias[col0];
#pragma unroll
    for (int i = 0; i < 4; ++i) {
      float4 o;
      o.x = acc[i][0] + bb4.x;
      o.y = acc[i][1] + bb4.y;
      o.z = acc[i][2] + bb4.z;
      o.w = acc[i][3] + bb4.w;
      *(float4*)&C[(long)(row0 + i) * ldc + col0] = o;
    }
  } else {
#pragma unroll
    for (int i = 0; i < 4; ++i) {
      const int gr = blockIdx.y * 64 + (ty << 2) + i;
      const int b = gr >> 10;
      const int e = gr & 1023;
#pragma unroll
      for (int j = 0; j < 4; ++j) {
        const int col = blockIdx.x * 64 + (tx << 2) + j;
        C[(long)b * (ATTN_A * ENC_LEN) + (long)col * ENC_LEN + e] = acc[i][j];
      }
    }
  }
}

__global__ __launch_bounds__(256) void logits_fb(const float* __restrict__ peT,
                                                 const float* __restrict__ pd,
                                                 const float* __restrict__ v,
                                                 float* __restrict__ out) {
  const int tid = threadIdx.x;
  const int e = blockIdx.x * 256 + tid;
  const int d0 = blockIdx.y * 8;
  const int b = blockIdx.z;

  __shared__ float cpd[ATTN_A][8];
  __shared__ float vv[ATTN_A];

  {
    const int a = tid;
#pragma unroll
    for (int dd = 0; dd < 8; ++dd)
      cpd[a][dd] = C2F * pd[((b * DEC_LEN + d0 + dd) * ATTN_A) + a];
    vv[a] = -2.0f * v[a];
  }
  __syncthreads();

  float acc[8] = {0.f, 0.f, 0.f, 0.f, 0.f, 0.f, 0.f, 0.f};
  const float* pe = peT + (long)b * (ATTN_A * ENC_LEN) + e;

  for (int a = 0; a < ATTN_A; a += 4) {
    float pes[4];
#pragma unroll
    for (int u = 0; u < 4; ++u) pes[u] = pe[(long)(a + u) * ENC_LEN];
#pragma unroll
    for (int u = 0; u < 4; ++u) {
      const float cpe = C2F * pes[u];
      const float vu = vv[a + u];
      const float4 c0 = *(const float4*)&cpd[a + u][0];
      const float4 c1 = *(const float4*)&cpd[a + u][4];
      const float cd[8] = {c0.x, c0.y, c0.z, c0.w, c1.x, c1.y, c1.z, c1.w};
#pragma unroll
      for (int dd = 0; dd < 8; ++dd) {
        const float x = cd[dd] + cpe;
        const float ex = __builtin_amdgcn_exp2f(x);
        const float r = __builtin_amdgcn_rcpf(ex + 1.0f);
        acc[dd] = fmaf(vu, r, acc[dd]);
      }
    }
  }

  const long base = ((long)(b * DEC_LEN + d0) * ENC_LEN) + e;
#pragma unroll
  for (int dd = 0; dd < 8; ++dd) out[base + (long)dd * ENC_LEN] = acc[dd];
}

__global__ __launch_bounds__(256) void softmax_fb(float* __restrict__ attn,
                                                  const float* __restrict__ mask) {
  const int row = blockIdx.x;
  const int b = row >> 8;
  const int tid = threadIdx.x;
  float* rp = attn + (long)row * ENC_LEN;
  const float* mp = mask + b * ENC_LEN;

  float l[4], m[4];
#pragma unroll
  for (int j = 0; j < 4; ++j) {
    l[j] = rp[tid + 256 * j];
    m[j] = mp[tid + 256 * j];
  }

  __shared__ float redmax[4];
  __shared__ float redsum[4];
  const int lane = tid & 63;
  const int wid = tid >> 6;

  float tm = fmaxf(fmaxf(l[0], l[1]), fmaxf(l[2], l[3]));
#pragma unroll
  for (int off = 1; off < 64; off <<= 1) tm = fmaxf(tm, __shfl_xor(tm, off, 64));
  if (lane == 0) redmax[wid] = tm;
  __syncthreads();
  const float rmax = fmaxf(fmaxf(redmax[0], redmax[1]), fmaxf(redmax[2], redmax[3]));

  const float LOG2E = 1.4426950408889634f;
  float p[4];
  float ts = 0.f;
#pragma unroll
  for (int j = 0; j < 4; ++j) {
    p[j] = __builtin_amdgcn_exp2f((l[j] - rmax) * LOG2E) * m[j];
    ts += p[j];
  }
#pragma unroll
  for (int off = 1; off < 64; off <<= 1) ts += __shfl_xor(ts, off, 64);
  if (lane == 0) redsum[wid] = ts;
  __syncthreads();
  const float rsum = redsum[0] + redsum[1] + redsum[2] + redsum[3];

  const float inv = 1.0f / rsum;
#pragma unroll
  for (int j = 0; j < 4; ++j) rp[tid + 256 * j] = p[j] * inv;
}

// ---------------------------------------------------------------------------
extern "C" void kernel_launch(void* const* d_in, const int* in_sizes, int n_in,
                              void* d_out, int out_size, void* d_ws, size_t ws_size,
                              hipStream_t stream) {
  const float* enc = (const float*)d_in[0];
  const float* dec = (const float*)d_in[1];
  const float* mask = (const float*)d_in[2];
  const float* Wh = (const float*)d_in[3];
  const float* Ws = (const float*)d_in[4];
  const float* bs = (const float*)d_in[5];
  const float* v = (const float*)d_in[6];

  float* ctx = (float*)d_out;                      // [4,256,1024]
  float* attn = ctx + (long)BB * DEC_LEN * ENC_H;  // [4,256,1024]

  // ws layout (fast path):
  //  pdE  f32 [1024][256]             1 MB   (exp2 pre-applied)
  //  peP  f32 [4][4et][256a][256eo]   4 MB   (E-TILED)
  //  p1,p2,p3 f32 [4][256][1024] each 12 MB (logits partials, aq=1..3)
  //  encT bf16 [4][1024h][1024e]      8 MB
  //  WhT/WsT bf16 [256][1024]         1 MB
  //  encB bf16 [4][1024e][1024h]      8 MB
  //  decB bf16 [1024][1024]           2 MB
  //  attnB bf16 [4][256][1024]        2 MB
  const long N_PD = 1024L * ATTN_A;
  const long N_PE = (long)BB * ATTN_A * ENC_LEN;
  const long N_P1 = (long)BB * DEC_LEN * ENC_LEN;
  const long N_ENC = (long)BB * ENC_H * ENC_LEN;
  const long N_W = (long)ATTN_A * ENC_H;
  const long N_DEC = 1024L * ENC_H;
  const long N_ATT = (long)BB * DEC_LEN * ENC_LEN;
  const size_t FAST_WS = (N_PD + N_PE + 3 * N_P1) * 4 +
                         (N_ENC + 2 * N_W + N_ENC + N_DEC + N_ATT) * 2;

  if (ws_size >= FAST_WS) {
    float* pdE = (float*)d_ws;
    float* peP = pdE + N_PD;
    float* p1 = peP + N_PE;
    float* p2 = p1 + N_P1;
    float* p3 = p2 + N_P1;
    unsigned short* encT = (unsigned short*)(p3 + N_P1);
    unsigned short* WhT = encT + N_ENC;
    unsigned short* WsT = WhT + N_W;
    unsigned short* encB = WsT + N_W;
    unsigned short* decB = encB + N_ENC;
    unsigned short* attnB = decB + N_DEC;

    // 1) all transposes + bf16 conversions
    prep_k<<<dim3(1408, 1, 1), 256, 0, stream>>>(Wh, Ws, enc, dec, WhT, WsT, encT,
                                                 encB, decB);
    // 2) projections, tile 32x64, full K; pd-epilogue applies bias+exp2
    pgemm<<<dim3(4, 160, 1), 256, 0, stream>>>(decB, encB, WsT, WhT, bs, pdE, peP);
    // 3) logits partials: dd=16, a-split x4 -> 1024 blocks
    logits_k<<<dim3(4, 16, BB * 4), 256, 0, stream>>>(peP, pdE, v, attn, p1, p2, p3);
    // 4) masked softmax (sum of 4 partials) -> attn (fp32) + attnB (bf16)
    softmax4_k<<<dim3(BB * DEC_LEN, 1, 1), 256, 0, stream>>>(attn, p1, p2, p3, mask,
                                                             attnB);
    // 5) ctx GEMM, tile 32x64, full K, direct write
    cgemm<<<dim3(16, 8, BB), 256, 0, stream>>>(attnB, encT, ctx);
  } else {
    // fallback: proven fp32 path (5 MB ws)
    float* pd = (float*)d_ws;
    float* peT = pd + (long)BB * DEC_LEN * ATTN_A;

    gemm64<0, true><<<dim3(ATTN_A / 64, (BB * DEC_LEN) / 64, 1), 256, 0, stream>>>(
        dec, Ws, bs, pd, ENC_H, ENC_H, ATTN_A, ATTN_A, 0, 0, 0);
    gemm64<1, false><<<dim3(ATTN_A / 64, (BB * ENC_LEN) / 64, 1), 256, 0, stream>>>(
        enc, Wh, nullptr, peT, ENC_H, ENC_H, ATTN_A, 0, 0, 0, 0);
    logits_fb<<<dim3(ENC_LEN / 256, DEC_LEN / 8, BB), 256, 0, stream>>>(peT, pd, v,
                                                                        attn);
    softmax_fb<<<dim3(BB * DEC_LEN, 1, 1), 256, 0, stream>>>(attn, mask);
    gemm64<0, false><<<dim3(ENC_H / 64, DEC_LEN / 64, BB), 256, 0, stream>>>(
        attn, enc, nullptr, ctx, ENC_LEN, ENC_LEN, ENC_H, ENC_H,
        (long)DEC_LEN * ENC_LEN, (long)ENC_LEN * ENC_H, (long)DEC_LEN * ENC_H);
  }
}